// Round 1
// baseline (79.483 us; speedup 1.0000x reference)
//
#include <hip/hip_runtime.h>
#include <float.h>
#include <math.h>

#define PPIL   40000
#define NPTS   32
#define CIN    4
#define COUT   64
#define NBLK_A 1250            // PPIL / 32 pillars per block
#define LDS_PSTRIDE 292        // 32*9 = 288 floats + 4 pad (bank spread)

__device__ __forceinline__ float shfl_xor_f(float v, int m) {
    return __shfl_xor(v, m, 64);
}

// ---------------------------------------------------------------------------
// Kernel A: augment feats -> LDS, 9->64 matmul, per-pillar raw max (to d_out),
//           per-block partial sums of x and x^2 per channel (to ws).
// ---------------------------------------------------------------------------
__global__ __launch_bounds__(256) void pfn_main(
    const float* __restrict__ features,     // [P][N][4]
    const int*   __restrict__ num_voxels,   // [P]
    const int*   __restrict__ coors,        // [P][4]
    const float* __restrict__ linear_w,     // [64][9]
    float*       __restrict__ rawmax,       // [P][64]  (aliases d_out)
    float*       __restrict__ partials)     // [NBLK_A][128]
{
    __shared__ float lds_f[32 * LDS_PSTRIDE];
    __shared__ float lds_red[4][8][16];

    const int tid = threadIdx.x;
    const int bid = blockIdx.x;
    const int pillar_base = bid * 32;

    // ---- phase 1: compute masked augmented feats into LDS ----
    {
        const int n   = tid & 31;   // point index
        const int pl0 = tid >> 5;   // 0..7
        #pragma unroll
        for (int g = 0; g < 4; ++g) {
            const int pl = g * 8 + pl0;          // 0..31
            const int p  = pillar_base + pl;
            const float4 f = *(const float4*)(features + ((size_t)p * NPTS + n) * CIN);

            // pillar xyz sum over ALL 32 points (reference sums full N)
            float sx = f.x, sy = f.y, sz = f.z;
            #pragma unroll
            for (int m = 16; m >= 1; m >>= 1) {
                sx += shfl_xor_f(sx, m);
                sy += shfl_xor_f(sy, m);
                sz += shfl_xor_f(sz, m);
            }
            const int   nv     = num_voxels[p];
            const float inv_nv = 1.0f / (float)nv;
            const float mx_ = sx * inv_nv, my_ = sy * inv_nv, mz_ = sz * inv_nv;

            const int ccy = coors[p * 4 + 2];
            const int ccx = coors[p * 4 + 3];
            const float f7 = f.x - ((float)ccx * 0.2f + 0.1f);     // VX, X_OFF
            const float f8 = f.y - ((float)ccy * 0.2f - 39.9f);    // VY, Y_OFF

            const float msk = (n < nv) ? 1.0f : 0.0f;
            float* dst = &lds_f[pl * LDS_PSTRIDE + n * 9];
            dst[0] = f.x * msk;
            dst[1] = f.y * msk;
            dst[2] = f.z * msk;
            dst[3] = f.w * msk;
            dst[4] = (f.x - mx_) * msk;
            dst[5] = (f.y - my_) * msk;
            dst[6] = (f.z - mz_) * msk;
            dst[7] = f7 * msk;
            dst[8] = f8 * msk;
        }
    }
    __syncthreads();

    // ---- phase 2: 8 threads per pillar, 8 channels each (u = cg + 8k) ----
    const int pl2 = tid >> 3;   // pillar in block, 0..31
    const int cg  = tid & 7;    // channel group

    float w[8][9];
    #pragma unroll
    for (int k = 0; k < 8; ++k) {
        const float* wr = linear_w + (cg + 8 * k) * 9;
        #pragma unroll
        for (int c = 0; c < 9; ++c) w[k][c] = wr[c];
    }

    float s1[8], s2[8], mx[8];
    #pragma unroll
    for (int k = 0; k < 8; ++k) { s1[k] = 0.0f; s2[k] = 0.0f; mx[k] = -FLT_MAX; }

    const float* fbase = &lds_f[pl2 * LDS_PSTRIDE];
    for (int n = 0; n < NPTS; ++n) {
        const float* fp = fbase + n * 9;
        const float f0 = fp[0], f1 = fp[1], f2 = fp[2], f3 = fp[3], f4 = fp[4];
        const float f5 = fp[5], f6 = fp[6], f7 = fp[7], f8 = fp[8];
        #pragma unroll
        for (int k = 0; k < 8; ++k) {
            float x = w[k][0] * f0;
            x = fmaf(w[k][1], f1, x);
            x = fmaf(w[k][2], f2, x);
            x = fmaf(w[k][3], f3, x);
            x = fmaf(w[k][4], f4, x);
            x = fmaf(w[k][5], f5, x);
            x = fmaf(w[k][6], f6, x);
            x = fmaf(w[k][7], f7, x);
            x = fmaf(w[k][8], f8, x);
            s1[k] += x;
            s2[k] = fmaf(x, x, s2[k]);
            mx[k] = fmaxf(mx[k], x);
        }
    }

    // raw max -> rawmax (d_out), channel u = cg + 8k
    {
        float* rp = rawmax + (size_t)(pillar_base + pl2) * COUT + cg;
        #pragma unroll
        for (int k = 0; k < 8; ++k) rp[8 * k] = mx[k];
    }

    // reduce s1/s2 across lanes with equal (lane & 7)
    #pragma unroll
    for (int k = 0; k < 8; ++k) {
        #pragma unroll
        for (int m = 8; m <= 32; m <<= 1) {
            s1[k] += shfl_xor_f(s1[k], m);
            s2[k] += shfl_xor_f(s2[k], m);
        }
    }
    const int lane = tid & 63;
    const int wv   = tid >> 6;
    if (lane < 8) {
        #pragma unroll
        for (int k = 0; k < 8; ++k) {
            lds_red[wv][lane][k]     = s1[k];
            lds_red[wv][lane][8 + k] = s2[k];
        }
    }
    __syncthreads();
    if (tid < 128) {
        const int cg2 = tid >> 4, v = tid & 15;
        const float acc = lds_red[0][cg2][v] + lds_red[1][cg2][v] +
                          lds_red[2][cg2][v] + lds_red[3][cg2][v];
        partials[bid * 128 + tid] = acc;
    }
}

// ---------------------------------------------------------------------------
// Kernel B: reduce partials (double), finalize BN scale/bias.
// partial layout per block: [cg][k] = sum of channel u=cg+8k, [cg][8+k] = sumsq
// ---------------------------------------------------------------------------
__global__ __launch_bounds__(128) void pfn_stats(
    const float* __restrict__ partials,
    const float* __restrict__ gamma,
    const float* __restrict__ beta,
    float*       __restrict__ stats)   // scale[64], bias[64]
{
    const int t = threadIdx.x;  // 0..127
    double acc = 0.0;
    for (int b = 0; b < NBLK_A; ++b) acc += (double)partials[b * 128 + t];

    __shared__ double red[128];
    red[t] = acc;
    __syncthreads();

    if (t < 64) {
        const int cg = t & 7, k = t >> 3;       // u = cg + 8k
        const double s1 = red[cg * 16 + k];
        const double s2 = red[cg * 16 + 8 + k];
        const double PN = (double)PPIL * (double)NPTS;
        const double mean = s1 / PN;
        const double var  = s2 / PN - mean * mean;
        const double scale = (double)gamma[t] / sqrt(var + 1e-3);
        const double bias  = (double)beta[t] - mean * scale;
        stats[t]      = (float)scale;
        stats[64 + t] = (float)bias;
    }
}

// ---------------------------------------------------------------------------
// Kernel C: out = relu(rawmax * scale + bias), in place on d_out.
// ---------------------------------------------------------------------------
__global__ __launch_bounds__(256) void pfn_final(
    float* __restrict__ out,
    const float* __restrict__ stats,
    int total4)
{
    const int i = blockIdx.x * blockDim.x + threadIdx.x;
    if (i >= total4) return;
    const int u0 = (i & 15) * 4;     // 4 consecutive channels
    float4 v = ((float4*)out)[i];
    v.x = fmaxf(fmaf(v.x, stats[u0 + 0], stats[64 + u0 + 0]), 0.0f);
    v.y = fmaxf(fmaf(v.y, stats[u0 + 1], stats[64 + u0 + 1]), 0.0f);
    v.z = fmaxf(fmaf(v.z, stats[u0 + 2], stats[64 + u0 + 2]), 0.0f);
    v.w = fmaxf(fmaf(v.w, stats[u0 + 3], stats[64 + u0 + 3]), 0.0f);
    ((float4*)out)[i] = v;
}

// ---------------------------------------------------------------------------
extern "C" void kernel_launch(void* const* d_in, const int* in_sizes, int n_in,
                              void* d_out, int out_size, void* d_ws, size_t ws_size,
                              hipStream_t stream) {
    const float* features   = (const float*)d_in[0];
    const int*   num_voxels = (const int*)d_in[1];
    const int*   coors      = (const int*)d_in[2];
    const float* linear_w   = (const float*)d_in[3];
    const float* gamma      = (const float*)d_in[4];
    const float* beta       = (const float*)d_in[5];
    // d_in[6] = batch_size (unused)

    float* out = (float*)d_out;               // used as rawmax scratch, then finalized
    float* wsf = (float*)d_ws;
    float* partials = wsf;                    // NBLK_A * 128 floats = 640 KB
    float* stats    = wsf + NBLK_A * 128;     // 128 floats

    pfn_main<<<NBLK_A, 256, 0, stream>>>(features, num_voxels, coors, linear_w,
                                         out, partials);
    pfn_stats<<<1, 128, 0, stream>>>(partials, gamma, beta, stats);

    const int total4 = PPIL * COUT / 4;       // 640000
    pfn_final<<<(total4 + 255) / 256, 256, 0, stream>>>(out, stats, total4);
}